// Round 1
// baseline (847.004 us; speedup 1.0000x reference)
//
#include <hip/hip_runtime.h>

// Sparsemax along last dim, n = 2048, fp32.
// One 64-lane wave per row; 32 elements/lane in registers.
// Michelot's exact simplex-projection iteration (no sort):
//   tau_0 = (sum(x) - 1)/n
//   repeat: S = {x > tau}; tau = (sum_S x - 1)/|S|;  until |S| stable.
// tau is monotone non-decreasing => support only shrinks => |S| equal
// implies set equal implies exact fixed point. Ties at tau leave tau
// unchanged, so output matches the sort-based reference up to rounding.

#define ROW_N 2048
#define LANES 64
#define EPL   32   // elements per lane
#define CHUNKS 8   // 8 chunks of (64 lanes x float4) = 2048 floats

__global__ __launch_bounds__(256) void sparsemax_rows_kernel(
    const float* __restrict__ in, float* __restrict__ out, int nrows)
{
    const int wave = threadIdx.x >> 6;
    const int lane = threadIdx.x & 63;
    const int row  = blockIdx.x * 4 + wave;
    if (row >= nrows) return;

    const float* __restrict__ rp = in  + (size_t)row * ROW_N;
    float*       __restrict__ wp = out + (size_t)row * ROW_N;

    // ---- load row: 8 coalesced float4 per lane --------------------------
    float v[EPL];
    #pragma unroll
    for (int c = 0; c < CHUNKS; ++c) {
        const float4 f = *reinterpret_cast<const float4*>(rp + c * 256 + lane * 4);
        v[c * 4 + 0] = f.x; v[c * 4 + 1] = f.y;
        v[c * 4 + 2] = f.z; v[c * 4 + 3] = f.w;
    }

    // ---- row max (shift for numerical hygiene, as reference does) ------
    float m = v[0];
    #pragma unroll
    for (int i = 1; i < EPL; ++i) m = fmaxf(m, v[i]);
    #pragma unroll
    for (int off = 1; off < LANES; off <<= 1)
        m = fmaxf(m, __shfl_xor(m, off, LANES));

    float s = 0.0f;
    #pragma unroll
    for (int i = 0; i < EPL; ++i) { v[i] -= m; s += v[i]; }
    #pragma unroll
    for (int off = 1; off < LANES; off <<= 1)
        s += __shfl_xor(s, off, LANES);

    // ---- Michelot iteration --------------------------------------------
    float tau    = (s - 1.0f) * (1.0f / (float)ROW_N);
    float prev_k = (float)ROW_N;

    for (int iter = 0; iter < 64; ++iter) {
        float ls = 0.0f, lk = 0.0f;
        #pragma unroll
        for (int i = 0; i < EPL; ++i) {
            const bool gt = v[i] > tau;
            ls += gt ? v[i] : 0.0f;
            lk += gt ? 1.0f : 0.0f;
        }
        #pragma unroll
        for (int off = 1; off < LANES; off <<= 1) {
            ls += __shfl_xor(ls, off, LANES);
            lk += __shfl_xor(lk, off, LANES);
        }
        // counts are exact small integers in fp32; uniform across the wave
        if (lk == prev_k) break;   // support stable -> tau is the fixed point
        prev_k = lk;
        tau = (ls - 1.0f) / lk;
    }

    // ---- epilogue: y = max(0, x - tau), coalesced float4 stores --------
    #pragma unroll
    for (int c = 0; c < CHUNKS; ++c) {
        float4 f;
        f.x = fmaxf(0.0f, v[c * 4 + 0] - tau);
        f.y = fmaxf(0.0f, v[c * 4 + 1] - tau);
        f.z = fmaxf(0.0f, v[c * 4 + 2] - tau);
        f.w = fmaxf(0.0f, v[c * 4 + 3] - tau);
        *reinterpret_cast<float4*>(wp + c * 256 + lane * 4) = f;
    }
}

extern "C" void kernel_launch(void* const* d_in, const int* in_sizes, int n_in,
                              void* d_out, int out_size, void* d_ws, size_t ws_size,
                              hipStream_t stream)
{
    const float* in = (const float*)d_in[0];
    float* out = (float*)d_out;
    const int nrows = in_sizes[0] / ROW_N;          // 65536
    const int blocks = (nrows + 3) / 4;             // 4 rows (waves) per block
    sparsemax_rows_kernel<<<blocks, 256, 0, stream>>>(in, out, nrows);
}